// Round 1
// baseline (254.488 us; speedup 1.0000x reference)
//
#include <hip/hip_runtime.h>

// B=8, H=W=48 -> 2304 positions, C=256 channels.
// raw[b,ij,kl] = sum_c A[b,ij,c]*B[b,kl,c]
// out = raw / sqrt(sum_ij raw^2)       (the reference's 1/C cancels in the norm)
//
// R3: replace the full 21.7 GF "norm-only" GEMM pass with the quadratic form
//   colSq[b,kl] = B[kl]^T (A^T A) B[kl]
// pipeline:
//   1. convert fp32->bf16 (A row-major, A^T c-major via LDS transpose, B row-major)
//   2. gram_partial: G = A^T A  (K-split x6, fp32 atomics; 2.4 GF total)
//   3. g_to_bf: G fp32 -> bf16
//   4. colsq: M = B*G (MFMA), colSq[kl] = sum_c M[kl,c]*B[kl,c]  (2.4 GF)
//   5. corr_out: output GEMM, divide by rsqrt(colSq)  (unchanged from R2)

#define HW2 2304
#define CH  256
#define NB  8
#define NELEM (NB * HW2 * CH)   // 4,718,592 per input
#define KS  6                   // gram K-split: 2304/6 = 384 = 6 x 64

typedef __attribute__((ext_vector_type(8))) short bf16x8;   // 8 bf16 = 4 VGPRs
typedef __attribute__((ext_vector_type(4))) float f32x4;    // MFMA acc

static __device__ inline unsigned short f2bf(float f) {
    union { float f; unsigned u; } x; x.f = f;
    unsigned r = x.u + 0x7FFFu + ((x.u >> 16) & 1u);
    return (unsigned short)(r >> 16);
}

static __device__ inline float bf2f(unsigned short u) {
    union { unsigned u; float f; } x; x.u = ((unsigned)u) << 16;
    return x.f;
}

// async global->LDS, 16B per lane (global_load_lds_dwordx4)
static __device__ inline void async_copy16(const void* g, void* l) {
    __builtin_amdgcn_global_load_lds(
        (const __attribute__((address_space(1))) unsigned int*)g,
        (__attribute__((address_space(3))) unsigned int*)l, 16, 0, 0);
}

// ---------------------------------------------------------------------------
// 1. convert: A,B fp32 -> bf16 row-major; additionally A^T (c-major) for gram.
//    64x64 tiles; 1152 A-tiles (with transpose) + 1152 B-tiles.
// ---------------------------------------------------------------------------
__global__ __launch_bounds__(256) void convert_bf16(const float* __restrict__ A,
                                                    const float* __restrict__ B,
                                                    unsigned short* __restrict__ Abf,
                                                    unsigned short* __restrict__ Bbf,
                                                    unsigned short* __restrict__ Atbf) {
    __shared__ unsigned short t[64][65];   // +1 pad breaks transpose bank conflicts
    const int blk = blockIdx.x;            // 0..2303
    const bool isA = blk < 1152;
    const int tb = isA ? blk : blk - 1152;
    const int b  = tb / 144;               // 144 tiles per batch = 36 ij x 4 c
    const int tt = tb % 144;
    const int ijt = tt >> 2, ct = tt & 3;
    const size_t base = ((size_t)b * HW2 + (size_t)ijt * 64) * CH + ct * 64;
    const float* src = (isA ? A : B) + base;
    unsigned short* dst = (isA ? Abf : Bbf) + base;
    const int tid = threadIdx.x;
    const int lr = tid & 15, rq = tid >> 4;
#pragma unroll
    for (int p = 0; p < 4; p++) {
        const int row = rq + p * 16;
        float4 v = *(const float4*)(src + (size_t)row * CH + lr * 4);
        ushort4 u;
        u.x = f2bf(v.x); u.y = f2bf(v.y); u.z = f2bf(v.z); u.w = f2bf(v.w);
        *(ushort4*)(dst + (size_t)row * CH + lr * 4) = u;
        if (isA) {
            t[row][lr * 4 + 0] = u.x; t[row][lr * 4 + 1] = u.y;
            t[row][lr * 4 + 2] = u.z; t[row][lr * 4 + 3] = u.w;
        }
    }
    if (isA) {
        __syncthreads();
#pragma unroll
        for (int p = 0; p < 4; p++) {
            const int c = rq + p * 16;     // channel = transposed row
            ushort4 u;
            u.x = t[lr * 4 + 0][c]; u.y = t[lr * 4 + 1][c];
            u.z = t[lr * 4 + 2][c]; u.w = t[lr * 4 + 3][c];
            *(ushort4*)(Atbf + ((size_t)b * CH + (size_t)(ct * 64 + c)) * HW2
                        + (size_t)ijt * 64 + lr * 4) = u;
        }
    }
}

// ---------------------------------------------------------------------------
// 2. gram_partial: G[b] += At[rows] . At[rows]^T over a 384-wide K chunk.
//    grid (2,2,8*KS) = 192 blocks -> enough TLP to hide the 6-iter K loop.
// ---------------------------------------------------------------------------
__global__ __launch_bounds__(256) void gram_partial(const unsigned short* __restrict__ Atbf,
                                                    float* __restrict__ Gf) {
    __shared__ unsigned short As[2 * 128 * 32];
    __shared__ unsigned short Bs[2 * 128 * 32];
    const int tid = threadIdx.x;
    const int bx = blockIdx.x, by = blockIdx.y;
    const int b  = blockIdx.z / KS, ks = blockIdx.z % KS;
    const int kt0 = ks * (HW2 / KS);

    const unsigned short* Ar = Atbf + ((size_t)b * CH + by * 128) * HW2;
    const unsigned short* Br = Atbf + ((size_t)b * CH + bx * 128) * HW2;

    const int srow = tid >> 2, skcol = (tid & 3) * 8;
    const int wave = tid >> 6, lane = tid & 63;
    const int wm = (wave >> 1) * 64, wn = (wave & 1) * 64;
    const int lr = lane & 15, quad = lane >> 4, k8 = quad * 8;

    f32x4 acc[4][4];
#pragma unroll
    for (int i = 0; i < 4; i++)
#pragma unroll
        for (int j = 0; j < 4; j++) acc[i][j] = (f32x4){0.f, 0.f, 0.f, 0.f};

    for (int kt = kt0; kt < kt0 + HW2 / KS; kt += 64) {
#pragma unroll
        for (int c = 0; c < 2; c++) {
            const int kof = kt + c * 32;
#pragma unroll
            for (int i = 0; i < 2; i++) {
                async_copy16(Ar + (size_t)(srow + i * 64) * HW2 + kof + skcol,
                             &As[c * 4096 + tid * 8 + i * 2048]);
                async_copy16(Br + (size_t)(srow + i * 64) * HW2 + kof + skcol,
                             &Bs[c * 4096 + tid * 8 + i * 2048]);
            }
        }
        __syncthreads();
#pragma unroll
        for (int c = 0; c < 2; c++) {
            bf16x8 af[4], bfr[4];
#pragma unroll
            for (int mt = 0; mt < 4; mt++)
                af[mt] = *(const bf16x8*)&As[c * 4096 + (wm + mt * 16 + lr) * 32 + k8];
#pragma unroll
            for (int nt = 0; nt < 4; nt++)
                bfr[nt] = *(const bf16x8*)&Bs[c * 4096 + (wn + nt * 16 + lr) * 32 + k8];
#pragma unroll
            for (int mt = 0; mt < 4; mt++)
#pragma unroll
                for (int nt = 0; nt < 4; nt++)
                    acc[mt][nt] = __builtin_amdgcn_mfma_f32_16x16x32_bf16(
                        af[mt], bfr[nt], acc[mt][nt], 0, 0, 0);
        }
        __syncthreads();
    }
#pragma unroll
    for (int mt = 0; mt < 4; mt++)
#pragma unroll
        for (int nt = 0; nt < 4; nt++) {
            f32x4 v = acc[mt][nt];
            const int row = by * 128 + wm + mt * 16 + quad * 4;
            const int col = bx * 128 + wn + nt * 16 + lr;
#pragma unroll
            for (int r = 0; r < 4; r++)
                atomicAdd(&Gf[((size_t)b * CH + row + r) * CH + col], v[r]);
        }
}

// ---------------------------------------------------------------------------
// 3. G fp32 -> bf16 (8*256*256 = 524288 elems)
// ---------------------------------------------------------------------------
__global__ __launch_bounds__(256) void g_to_bf(const float* __restrict__ Gf,
                                               unsigned short* __restrict__ Gbf) {
    const int i = blockIdx.x * 256 + threadIdx.x;   // 131072 threads x float4
    float4 v = ((const float4*)Gf)[i];
    ushort4 u;
    u.x = f2bf(v.x); u.y = f2bf(v.y); u.z = f2bf(v.z); u.w = f2bf(v.w);
    ((ushort4*)Gbf)[i] = u;
}

// ---------------------------------------------------------------------------
// 4. colsq: M = B . G (G symmetric, row-major), colSq[kl] += sum_c M[kl,c]*B[kl,c]
//    grid (2 c-tiles, 18 kl-tiles, 8 batches) = 288 blocks, K=256 (4 iters).
// ---------------------------------------------------------------------------
__global__ __launch_bounds__(256) void colsq_pass(const unsigned short* __restrict__ Bbf,
                                                  const unsigned short* __restrict__ Gbf,
                                                  float* __restrict__ colSqG) {
    __shared__ unsigned short As[2 * 128 * 32];
    __shared__ unsigned short Bs[2 * 128 * 32];
    const int tid = threadIdx.x;
    const int bx = blockIdx.x;   // c tile (output cols)
    const int by = blockIdx.y;   // kl tile (output rows)
    const int b  = blockIdx.z;

    const unsigned short* Ab = Bbf + ((size_t)b * HW2 + by * 128) * CH;
    const unsigned short* Gb = Gbf + ((size_t)b * CH + bx * 128) * CH;

    const int srow = tid >> 2, skcol = (tid & 3) * 8;
    const int wave = tid >> 6, lane = tid & 63;
    const int wm = (wave >> 1) * 64, wn = (wave & 1) * 64;
    const int lr = lane & 15, quad = lane >> 4, k8 = quad * 8;

    f32x4 acc[4][4];
#pragma unroll
    for (int i = 0; i < 4; i++)
#pragma unroll
        for (int j = 0; j < 4; j++) acc[i][j] = (f32x4){0.f, 0.f, 0.f, 0.f};

    for (int kt = 0; kt < CH; kt += 64) {
#pragma unroll
        for (int c = 0; c < 2; c++) {
            const int kof = kt + c * 32;
#pragma unroll
            for (int i = 0; i < 2; i++) {
                async_copy16(Ab + (size_t)(srow + i * 64) * CH + kof + skcol,
                             &As[c * 4096 + tid * 8 + i * 2048]);
                async_copy16(Gb + (size_t)(srow + i * 64) * CH + kof + skcol,
                             &Bs[c * 4096 + tid * 8 + i * 2048]);
            }
        }
        __syncthreads();
#pragma unroll
        for (int c = 0; c < 2; c++) {
            bf16x8 af[4], bfr[4];
#pragma unroll
            for (int mt = 0; mt < 4; mt++)
                af[mt] = *(const bf16x8*)&As[c * 4096 + (wm + mt * 16 + lr) * 32 + k8];
#pragma unroll
            for (int nt = 0; nt < 4; nt++)
                bfr[nt] = *(const bf16x8*)&Bs[c * 4096 + (wn + nt * 16 + lr) * 32 + k8];
#pragma unroll
            for (int mt = 0; mt < 4; mt++)
#pragma unroll
                for (int nt = 0; nt < 4; nt++)
                    acc[mt][nt] = __builtin_amdgcn_mfma_f32_16x16x32_bf16(
                        af[mt], bfr[nt], acc[mt][nt], 0, 0, 0);
        }
        __syncthreads();
    }

    // colSq[kl] = sum over c of M[kl,c] * B[kl,c]; row-reduce across 16 lanes.
    const unsigned short* Brow = Ab + bx * 128;     // B[kl0+row][c0+col]
#pragma unroll
    for (int mt = 0; mt < 4; mt++)
#pragma unroll
        for (int r = 0; r < 4; r++) {
            const int row = wm + mt * 16 + quad * 4 + r;
            float s = 0.f;
#pragma unroll
            for (int nt = 0; nt < 4; nt++) {
                const int col = wn + nt * 16 + lr;
                s += acc[mt][nt][r] * bf2f(Brow[(size_t)row * CH + col]);
            }
            s += __shfl_xor(s, 1); s += __shfl_xor(s, 2);
            s += __shfl_xor(s, 4); s += __shfl_xor(s, 8);
            if (lr == 0)
                atomicAdd(&colSqG[(size_t)b * HW2 + by * 128 + row], s);
        }
}

// ---------------------------------------------------------------------------
// 5. output GEMM + normalize (unchanged R2 structure, WRITE_OUT only)
// ---------------------------------------------------------------------------
__global__ __launch_bounds__(256) void corr_out(const unsigned short* __restrict__ Abf,
                                                const unsigned short* __restrict__ Bbf,
                                                const float* __restrict__ colSqG,
                                                float* __restrict__ out) {
    __shared__ unsigned short As[2 * 128 * 32];
    __shared__ unsigned short Bs[2 * 128 * 32];
    const int tid = threadIdx.x;

    // XCD swizzle: batch fastest -> each XCD works ~one batch (fits its L2)
    const int lin = blockIdx.x + 18 * (blockIdx.y + 18 * blockIdx.z);
    const int b  = lin & 7;
    const int r_ = lin >> 3;
    const int bx = r_ % 18;
    const int by = r_ / 18;

    const unsigned short* Ab = Abf + ((size_t)b * HW2 + (size_t)by * 128) * CH;
    const unsigned short* Bb = Bbf + ((size_t)b * HW2 + (size_t)bx * 128) * CH;

    const int srow = tid >> 2, skcol = (tid & 3) * 8;
    const int wave = tid >> 6, lane = tid & 63;
    const int wm = (wave >> 1) * 64, wn = (wave & 1) * 64;
    const int lr = lane & 15, quad = lane >> 4, k8 = quad * 8;

    f32x4 acc[4][4];
#pragma unroll
    for (int i = 0; i < 4; i++)
#pragma unroll
        for (int j = 0; j < 4; j++) acc[i][j] = (f32x4){0.f, 0.f, 0.f, 0.f};

    for (int kt = 0; kt < CH; kt += 64) {
#pragma unroll
        for (int c = 0; c < 2; c++) {
            const int kof = kt + c * 32;
#pragma unroll
            for (int i = 0; i < 2; i++) {
                async_copy16(Ab + (size_t)(srow + i * 64) * CH + kof + skcol,
                             &As[c * 4096 + tid * 8 + i * 2048]);
                async_copy16(Bb + (size_t)(srow + i * 64) * CH + kof + skcol,
                             &Bs[c * 4096 + tid * 8 + i * 2048]);
            }
        }
        __syncthreads();
#pragma unroll
        for (int c = 0; c < 2; c++) {
            bf16x8 af[4], bfr[4];
#pragma unroll
            for (int mt = 0; mt < 4; mt++)
                af[mt] = *(const bf16x8*)&As[c * 4096 + (wm + mt * 16 + lr) * 32 + k8];
#pragma unroll
            for (int nt = 0; nt < 4; nt++)
                bfr[nt] = *(const bf16x8*)&Bs[c * 4096 + (wn + nt * 16 + lr) * 32 + k8];
#pragma unroll
            for (int mt = 0; mt < 4; mt++)
#pragma unroll
                for (int nt = 0; nt < 4; nt++)
                    acc[mt][nt] = __builtin_amdgcn_mfma_f32_16x16x32_bf16(
                        af[mt], bfr[nt], acc[mt][nt], 0, 0, 0);
        }
        __syncthreads();
    }

    const int colBase = bx * 128 + wn;
    const size_t outBase = (size_t)b * HW2 * HW2;
#pragma unroll
    for (int nt = 0; nt < 4; nt++) {
        const int col = colBase + nt * 16 + lr;
        const float rinv = rsqrtf(colSqG[(size_t)b * HW2 + col]);
#pragma unroll
        for (int mt = 0; mt < 4; mt++) {
            const int row0 = by * 128 + wm + mt * 16 + quad * 4;
            f32x4 v = acc[mt][nt];
#pragma unroll
            for (int r = 0; r < 4; r++)
                out[outBase + (size_t)(row0 + r) * HW2 + col] = v[r] * rinv;
        }
    }
}

extern "C" void kernel_launch(void* const* d_in, const int* in_sizes, int n_in,
                              void* d_out, int out_size, void* d_ws, size_t ws_size,
                              hipStream_t stream) {
    const float* A = (const float*)d_in[0];
    const float* B = (const float*)d_in[1];
    float* out = (float*)d_out;

    unsigned short* Abf  = (unsigned short*)d_ws;          // NELEM bf16
    unsigned short* Bbf  = Abf + NELEM;                    // NELEM bf16
    unsigned short* Atbf = Bbf + NELEM;                    // NELEM bf16 (A^T, c-major)
    unsigned short* Gbf  = Atbf + NELEM;                   // 8*256*256 bf16
    float* Gf     = (float*)(Gbf + (size_t)NB * CH * CH);  // 8*256*256 f32
    float* colSqG = Gf + (size_t)NB * CH * CH;             // 8*2304 f32

    hipMemsetAsync(Gf, 0, (size_t)NB * CH * CH * sizeof(float), stream);
    hipMemsetAsync(colSqG, 0, (size_t)NB * HW2 * sizeof(float), stream);

    convert_bf16<<<2304, 256, 0, stream>>>(A, B, Abf, Bbf, Atbf);
    gram_partial<<<dim3(2, 2, NB * KS), 256, 0, stream>>>(Atbf, Gf);
    g_to_bf<<<512, 256, 0, stream>>>(Gf, Gbf);
    colsq_pass<<<dim3(2, 18, NB), 256, 0, stream>>>(Bbf, Gbf, colSqG);
    corr_out<<<dim3(18, 18, NB), 256, 0, stream>>>(Abf, Bbf, colSqG, out);
}